// Round 27
// baseline (3882.305 us; speedup 1.0000x reference)
//
#include <hip/hip_runtime.h>
#include <math.h>

#pragma clang fp contract(off)

#define N      4096
#define INSZ   1024
#define KSP    8
#define NSTEP  100
#define NBS    16      // sim blocks; block owns 256 columns
#define CPB    256     // columns per sim block
#define NCH    16      // deposit chunks (spike-list split)
#define NGRP   64      // global 64-col mask groups
#define ICH    8       // input i-chunks
#define JG     32      // input col-groups (128 cols each)

// Static device scratch; g_pub cleared by k_prep each call (graph-replay safe).
__device__ float              g_I[NSTEP * N];                 // 1.6 MB
__device__ float              g_part[ICH * NSTEP * N];        // 13.1 MB
__device__ unsigned char      g_dbin[(size_t)N * N];          // 16 MB
// publish words: [t][group][half] = (mask_half32 << 32) | (t+1)  — self-validating
__device__ unsigned long long g_pub[NSTEP * NGRP * 2];        // 102 KB

// ---------- dbin = clip((int)(d*100.0f)+1, 1, 5), float4/uchar4 + pub reset ----------
__global__ __launch_bounds__(256) void k_prep(const float4* __restrict__ delays4) {
    int idx = blockIdx.x * 256 + threadIdx.x;
    int stride = gridDim.x * 256;
    for (int f = idx; f < NSTEP * NGRP * 2; f += stride) g_pub[f] = 0ull;
    const int tot4 = (N / 4) * N;                 // recurrent rows are first N rows
    for (int e = idx; e < tot4; e += stride) {
        float4 d4 = delays4[e];
        uchar4 o;
        { float d = fmaxf(d4.x, 0.0f); int db = (int)__fmul_rn(d, 100.0f) + 1; o.x = (unsigned char)(db > 5 ? 5 : db); }
        { float d = fmaxf(d4.y, 0.0f); int db = (int)__fmul_rn(d, 100.0f) + 1; o.y = (unsigned char)(db > 5 ? 5 : db); }
        { float d = fmaxf(d4.z, 0.0f); int db = (int)__fmul_rn(d, 100.0f) + 1; o.z = (unsigned char)(db > 5 ? 5 : db); }
        { float d = fmaxf(d4.w, 0.0f); int db = (int)__fmul_rn(d, 100.0f) + 1; o.w = (unsigned char)(db > 5 ? 5 : db); }
        *(uchar4*)&g_dbin[(size_t)e * 4] = o;
    }
}

// ---------- input binning partials: block = (jg, ic), 128 cols x 128 i-rows ----------
__global__ __launch_bounds__(128) void k_input_part(const float* __restrict__ st,
                                                    const float* __restrict__ Wm,
                                                    const float* __restrict__ delays) {
    __shared__ float acc[NSTEP * 128];            // 51.2 KB
    int jg = blockIdx.x & (JG - 1);
    int ic = blockIdx.x / JG;
    int tid = threadIdx.x;
    int j = jg * 128 + tid;
    for (int b = 0; b < NSTEP; b++) acc[b * 128 + tid] = 0.0f;
    __syncthreads();
    int i0 = ic * (INSZ / ICH);
    for (int ii = 0; ii < INSZ / ICH; ii++) {
        int i = i0 + ii;
        size_t base = (size_t)(N + i) * N + j;
        float d = fmaxf(delays[base], 0.0f);
        float w = Wm[base];
        const float* sp = st + i * KSP;
        #pragma unroll
        for (int k = 0; k < KSP; k++) {
            float tt = __fadd_rn(sp[k], d);       // f32 add (== np t_arr)
            float q  = __fmul_rn(tt, 100.0f);     // f32 multiply (== np *1/DT)
            if (q < 100.0f) {                     // bin <= 99 (q >= 0 always)
                int b = (int)q;
                atomicAdd(&acc[b * 128 + tid], w);   // ds_add_f32, per-lane ordered
            }
        }
    }
    __syncthreads();
    for (int b = 0; b < NSTEP; b++)
        g_part[((size_t)ic * NSTEP + b) * N + j] = acc[b * 128 + tid];
}

// ---------- ordered 8-way reduce of input partials ----------
__global__ __launch_bounds__(256) void k_input_red() {
    int idx = blockIdx.x * 256 + threadIdx.x;
    int stride = gridDim.x * 256;
    for (int e = idx; e < NSTEP * N; e += stride) {
        float s = 0.0f;
        #pragma unroll
        for (int c = 0; c < ICH; c++)             // ascending ic == ascending i
            s = __fadd_rn(s, g_part[(size_t)c * NSTEP * N + e]);
        g_I[e] = s;
    }
}

// ---------- simulation: 16 blocks x 1024 threads, fence-free publish ----------
// waves 0-3: membrane (256 cols) + per-wave ballot publish
// wave 4   : poll 128 words + build ascending spike list
// wave 5   : prefetch next step's I_in slice into LDS ping-pong
// all      : 16-way deposit split (float4 Wm, uchar4 dbin, ds_add partials)
__global__ __launch_bounds__(1024, 1) void k_sim(const float* __restrict__ Wm,
                                                 float* __restrict__ out) {
    int tid  = threadIdx.x;
    int blk  = blockIdx.x;          // 0..15
    int lane = tid & 63;
    int wave = tid >> 6;            // 0..15

    __shared__ float          pbuf[NCH * 5 * CPB];   // [chunk][slot][col] 80 KB
    __shared__ float          Ibuf[2][CPB];          // I_in ping-pong, 2 KB
    __shared__ unsigned short list[N];               // ascending spike list, 8 KB
    __shared__ int            s_cnt;

    for (int e = tid; e < NCH * 5 * CPB; e += 1024) pbuf[e] = 0.0f;
    if (tid < CPB) Ibuf[0][tid] = g_I[0 * N + blk * CPB + tid];
    __syncthreads();

    int quad  = tid & 63;             // 0..63 -> 4 consecutive columns
    int chunk = tid >> 6;             // 0..15 -> spike-list chunk
    int col0  = blk * CPB + quad * 4;
    float v = 0.0f;                   // membrane state (waves 0-3 use it)

    for (int t = 0; t < NSTEP; t++) {
        int slot = t % 5;
        unsigned long long expseq = (unsigned long long)(t + 1);

        if (tid < CPB) {
            // ---- waves 0-3: membrane update + fence-free packed publish ----
            float bufv = 0.0f;
            #pragma unroll
            for (int c = 0; c < NCH; c++) {        // chunk-order reduce + clear
                int a = (c * 5 + slot) * CPB + tid;
                bufv = __fadd_rn(bufv, pbuf[a]);
                pbuf[a] = 0.0f;
            }
            float I  = __fadd_rn(Ibuf[t & 1][tid], bufv);
            float vn = __fadd_rn(__fadd_rn(v, __fmul_rn(0.1f, -v)), I);
            bool  spk = (vn >= 1.0f);
            float vo = spk ? 0.0f : vn;
            v = vo;
            unsigned long long m = __ballot(spk);
            if (lane == 0) {
                int g = blk * 4 + wave;            // global 64-col group
                unsigned long long w0 = ((m & 0xFFFFFFFFull) << 32) | expseq;
                unsigned long long w1 = ((m >> 32) << 32) | expseq;
                __hip_atomic_store(&g_pub[(t * NGRP + g) * 2 + 0], w0,
                                   __ATOMIC_RELAXED, __HIP_MEMORY_SCOPE_AGENT);
                __hip_atomic_store(&g_pub[(t * NGRP + g) * 2 + 1], w1,
                                   __ATOMIC_RELAXED, __HIP_MEMORY_SCOPE_AGENT);
            }
            out[t * N + blk * CPB + tid] = vo;     // off the critical path
        } else if (wave == 4) {
            // ---- wave 4: per-lane self-validating poll + build spike list ----
            unsigned long long w0, w1;
            do {
                w0 = __hip_atomic_load(&g_pub[(t * NGRP + lane) * 2 + 0],
                                       __ATOMIC_RELAXED, __HIP_MEMORY_SCOPE_AGENT);
            } while ((unsigned)w0 != (unsigned)expseq);
            do {
                w1 = __hip_atomic_load(&g_pub[(t * NGRP + lane) * 2 + 1],
                                       __ATOMIC_RELAXED, __HIP_MEMORY_SCOPE_AGENT);
            } while ((unsigned)w1 != (unsigned)expseq);
            unsigned long long mm = (w0 >> 32) | ((w1 >> 32) << 32);

            int pc = __popcll(mm);
            int incl = pc;
            #pragma unroll
            for (int o = 1; o < 64; o <<= 1) {
                int nbv = __shfl_up(incl, o, 64);
                if (lane >= o) incl += nbv;
            }
            int off = incl - pc;
            if (lane == 63) s_cnt = incl;
            while (mm) {
                int bb = __builtin_ctzll(mm);
                mm &= mm - 1;
                list[off++] = (unsigned short)((lane << 6) + bb);
            }
        } else if (wave == 5) {
            // ---- wave 5: prefetch next step's I_in slice ----
            if (t + 1 < NSTEP) {
                float4 iv = *(const float4*)&g_I[(t + 1) * N + blk * CPB + lane * 4];
                *(float4*)&Ibuf[(t + 1) & 1][lane * 4] = iv;
            }
        }
        __syncthreads();

        // ---- deposits: 16-way spike split, float4 cols, ds_add partials ----
        int S  = s_cnt;
        int lo = (S * chunk) >> 4;
        int hi = (S * (chunk + 1)) >> 4;
        float* pb = &pbuf[chunk * 5 * CPB];
        int cb = quad * 4;
        #pragma unroll 4
        for (int s = lo; s < hi; s++) {
            int i = (int)list[s];
            size_t base = (size_t)i * N + col0;
            float4 w4 = *(const float4*)&Wm[base];
            uchar4 d4 = *(const uchar4*)&g_dbin[base];
            int r0 = slot + d4.x; if (r0 >= 5) r0 -= 5;
            int r1 = slot + d4.y; if (r1 >= 5) r1 -= 5;
            int r2 = slot + d4.z; if (r2 >= 5) r2 -= 5;
            int r3 = slot + d4.w; if (r3 >= 5) r3 -= 5;
            atomicAdd(&pb[r0 * CPB + cb + 0], w4.x);
            atomicAdd(&pb[r1 * CPB + cb + 1], w4.y);
            atomicAdd(&pb[r2 * CPB + cb + 2], w4.z);
            atomicAdd(&pb[r3 * CPB + cb + 3], w4.w);
        }
        __syncthreads();
    }
}

extern "C" void kernel_launch(void* const* d_in, const int* in_sizes, int n_in,
                              void* d_out, int out_size, void* d_ws, size_t ws_size,
                              hipStream_t stream) {
    const float* st     = (const float*)d_in[0];   // (1024, 8)
    const float* Wm     = (const float*)d_in[1];   // (5120, 4096)
    const float* delays = (const float*)d_in[2];   // (5120, 4096)
    float* out = (float*)d_out;                    // (100, 4096)

    k_prep      <<<256, 256, 0, stream>>>((const float4*)delays);
    k_input_part<<<JG * ICH, 128, 0, stream>>>(st, Wm, delays);
    k_input_red <<<256, 256, 0, stream>>>();
    // 16 blocks: trivially co-resident; no grid.sync -> plain launch
    k_sim       <<<NBS, 1024, 0, stream>>>(Wm, out);
}

// Round 28
// 1415.393 us; speedup vs baseline: 2.7429x; 2.7429x over previous
//
#include <hip/hip_runtime.h>
#include <math.h>

#pragma clang fp contract(off)

#define N      4096
#define INSZ   1024
#define KSP    8
#define NSTEP  100
#define NB     64      // sim blocks; block owns 64 columns
#define CPB    64      // columns per sim block
#define NCH    16      // deposit chunks (spike-list split)
#define ICH    8       // input i-chunks
#define JG     32      // input col-groups (128 cols each)

// Static device scratch; g_pub cleared by k_prep each call (graph-replay safe).
__device__ float              g_I[NSTEP * N];                 // 1.6 MB
__device__ float              g_part[ICH * NSTEP * N];        // 13.1 MB
__device__ unsigned char      g_dbin[(size_t)N * N];          // 16 MB
// publish words: [t][block][half] = (mask_half32 << 32) | (t+1)  — self-validating
__device__ unsigned long long g_pub[NSTEP * NB * 2];          // 102 KB

// ---------- dbin = clip((int)(d*100.0f)+1, 1, 5), float4/uchar4 + pub reset ----------
__global__ __launch_bounds__(256) void k_prep(const float4* __restrict__ delays4) {
    int idx = blockIdx.x * 256 + threadIdx.x;
    int stride = gridDim.x * 256;
    for (int f = idx; f < NSTEP * NB * 2; f += stride) g_pub[f] = 0ull;
    const int tot4 = (N / 4) * N;                 // recurrent rows are first N rows
    for (int e = idx; e < tot4; e += stride) {
        float4 d4 = delays4[e];
        uchar4 o;
        { float d = fmaxf(d4.x, 0.0f); int db = (int)__fmul_rn(d, 100.0f) + 1; o.x = (unsigned char)(db > 5 ? 5 : db); }
        { float d = fmaxf(d4.y, 0.0f); int db = (int)__fmul_rn(d, 100.0f) + 1; o.y = (unsigned char)(db > 5 ? 5 : db); }
        { float d = fmaxf(d4.z, 0.0f); int db = (int)__fmul_rn(d, 100.0f) + 1; o.z = (unsigned char)(db > 5 ? 5 : db); }
        { float d = fmaxf(d4.w, 0.0f); int db = (int)__fmul_rn(d, 100.0f) + 1; o.w = (unsigned char)(db > 5 ? 5 : db); }
        *(uchar4*)&g_dbin[(size_t)e * 4] = o;
    }
}

// ---------- input binning partials: block = (jg, ic), 128 cols x 128 i-rows ----------
__global__ __launch_bounds__(128) void k_input_part(const float* __restrict__ st,
                                                    const float* __restrict__ Wm,
                                                    const float* __restrict__ delays) {
    __shared__ float acc[NSTEP * 128];            // 51.2 KB
    int jg = blockIdx.x & (JG - 1);
    int ic = blockIdx.x / JG;
    int tid = threadIdx.x;
    int j = jg * 128 + tid;
    for (int b = 0; b < NSTEP; b++) acc[b * 128 + tid] = 0.0f;
    __syncthreads();
    int i0 = ic * (INSZ / ICH);
    for (int ii = 0; ii < INSZ / ICH; ii++) {
        int i = i0 + ii;
        size_t base = (size_t)(N + i) * N + j;
        float d = fmaxf(delays[base], 0.0f);
        float w = Wm[base];
        const float* sp = st + i * KSP;
        #pragma unroll
        for (int k = 0; k < KSP; k++) {
            float tt = __fadd_rn(sp[k], d);       // f32 add (== np t_arr)
            float q  = __fmul_rn(tt, 100.0f);     // f32 multiply (== np *1/DT)
            if (q < 100.0f) {                     // bin <= 99 (q >= 0 always)
                int b = (int)q;
                atomicAdd(&acc[b * 128 + tid], w);   // ds_add_f32, per-lane ordered
            }
        }
    }
    __syncthreads();
    for (int b = 0; b < NSTEP; b++)
        g_part[((size_t)ic * NSTEP + b) * N + j] = acc[b * 128 + tid];
}

// ---------- ordered 8-way reduce of input partials ----------
__global__ __launch_bounds__(256) void k_input_red() {
    int idx = blockIdx.x * 256 + threadIdx.x;
    int stride = gridDim.x * 256;
    for (int e = idx; e < NSTEP * N; e += stride) {
        float s = 0.0f;
        #pragma unroll
        for (int c = 0; c < ICH; c++)             // ascending ic == ascending i
            s = __fadd_rn(s, g_part[(size_t)c * NSTEP * N + e]);
        g_I[e] = s;
    }
}

// ---------- simulation: 64 blocks x 256 threads, fence-free publish ----------
// wave0: membrane + publish (out write deferred);  wave1: merged poll + list;
// wave2: store step t-1's output row (drain overlaps phase A);  all: deposits.
__global__ __launch_bounds__(256, 1) void k_sim(const float* __restrict__ Wm,
                                                float* __restrict__ out) {
    int tid  = threadIdx.x;
    int blk  = blockIdx.x;
    int lane = tid & 63;

    __shared__ float          pbuf[NCH * 5 * CPB];   // [chunk][slot][col] 20 KB
    __shared__ float          I_lds[NSTEP * CPB];    // this block's I_in, 25.6 KB
    __shared__ float          Obuf[2][CPB];          // output ping-pong
    __shared__ unsigned short list[N];               // ascending spike list, 8 KB
    __shared__ int            s_cnt;

    for (int e = tid; e < NSTEP * CPB; e += 256) {   // preload I_in slice
        int t = e >> 6, c = e & 63;
        I_lds[e] = g_I[t * N + blk * CPB + c];
    }
    for (int e = tid; e < NCH * 5 * CPB; e += 256) pbuf[e] = 0.0f;
    __syncthreads();

    int quad  = tid & (NCH - 1);      // 0..15 -> 4 consecutive columns
    int chunk = tid >> 4;             // 0..15 -> spike-list chunk
    int col0  = blk * CPB + quad * 4;
    float v = 0.0f;                   // membrane state (wave 0 uses it)

    for (int t = 0; t < NSTEP; t++) {
        int slot = t % 5;
        unsigned long long expseq = (unsigned long long)(t + 1);

        if (tid < CPB) {
            // ---- wave 0: membrane update + fence-free packed publish ----
            float bufv = 0.0f;
            #pragma unroll
            for (int c = 0; c < NCH; c++) {        // chunk-order reduce + clear
                int a = (c * 5 + slot) * CPB + tid;
                bufv = __fadd_rn(bufv, pbuf[a]);
                pbuf[a] = 0.0f;
            }
            float I  = __fadd_rn(I_lds[t * CPB + tid], bufv);
            float vn = __fadd_rn(__fadd_rn(v, __fmul_rn(0.1f, -v)), I);
            bool  spk = (vn >= 1.0f);
            float vo = spk ? 0.0f : vn;
            v = vo;
            unsigned long long m = __ballot(spk);
            if (tid == 0) {
                unsigned long long w0 = ((m & 0xFFFFFFFFull) << 32) | expseq;
                unsigned long long w1 = ((m >> 32) << 32) | expseq;
                __hip_atomic_store(&g_pub[(t * NB + blk) * 2 + 0], w0,
                                   __ATOMIC_RELAXED, __HIP_MEMORY_SCOPE_AGENT);
                __hip_atomic_store(&g_pub[(t * NB + blk) * 2 + 1], w1,
                                   __ATOMIC_RELAXED, __HIP_MEMORY_SCOPE_AGENT);
            }
            Obuf[t & 1][tid] = vo;                 // LDS only; store deferred
        } else if (tid < 128) {
            // ---- wave 1: merged self-validating poll + build spike list ----
            unsigned long long w0, w1;
            do {
                w0 = __hip_atomic_load(&g_pub[(t * NB + lane) * 2 + 0],
                                       __ATOMIC_RELAXED, __HIP_MEMORY_SCOPE_AGENT);
                w1 = __hip_atomic_load(&g_pub[(t * NB + lane) * 2 + 1],
                                       __ATOMIC_RELAXED, __HIP_MEMORY_SCOPE_AGENT);
            } while ((unsigned)w0 != (unsigned)expseq ||
                     (unsigned)w1 != (unsigned)expseq);
            unsigned long long mm = (w0 >> 32) | ((w1 >> 32) << 32);

            int pc = __popcll(mm);
            int incl = pc;
            #pragma unroll
            for (int o = 1; o < 64; o <<= 1) {
                int nbv = __shfl_up(incl, o, 64);
                if (lane >= o) incl += nbv;
            }
            int off = incl - pc;
            if (lane == 63) s_cnt = incl;
            while (mm) {
                int bb = __builtin_ctzll(mm);
                mm &= mm - 1;
                list[off++] = (unsigned short)((lane << 6) + bb);
            }
        } else if (tid < 192) {
            // ---- wave 2: store previous step's output (drain overlaps phase) ----
            if (t > 0)
                out[(t - 1) * N + blk * CPB + lane] = Obuf[(t - 1) & 1][lane];
        }
        __syncthreads();

        // ---- deposits: 16-way spike split, float4 cols, ds_add_f32 partials ----
        int S  = s_cnt;
        int lo = (S * chunk) >> 4;
        int hi = (S * (chunk + 1)) >> 4;
        float* pb = &pbuf[chunk * 5 * CPB];
        int cb = quad * 4;
        #pragma unroll 4
        for (int s = lo; s < hi; s++) {
            int i = (int)list[s];
            size_t base = (size_t)i * N + col0;
            float4 w4 = *(const float4*)&Wm[base];
            uchar4 d4 = *(const uchar4*)&g_dbin[base];
            int r0 = slot + d4.x; if (r0 >= 5) r0 -= 5;
            int r1 = slot + d4.y; if (r1 >= 5) r1 -= 5;
            int r2 = slot + d4.z; if (r2 >= 5) r2 -= 5;
            int r3 = slot + d4.w; if (r3 >= 5) r3 -= 5;
            atomicAdd(&pb[r0 * CPB + cb + 0], w4.x);
            atomicAdd(&pb[r1 * CPB + cb + 1], w4.y);
            atomicAdd(&pb[r2 * CPB + cb + 2], w4.z);
            atomicAdd(&pb[r3 * CPB + cb + 3], w4.w);
        }
        __syncthreads();
    }

    // final output row (t = NSTEP-1)
    if (tid < CPB)
        out[(NSTEP - 1) * N + blk * CPB + tid] = Obuf[(NSTEP - 1) & 1][tid];
}

extern "C" void kernel_launch(void* const* d_in, const int* in_sizes, int n_in,
                              void* d_out, int out_size, void* d_ws, size_t ws_size,
                              hipStream_t stream) {
    const float* st     = (const float*)d_in[0];   // (1024, 8)
    const float* Wm     = (const float*)d_in[1];   // (5120, 4096)
    const float* delays = (const float*)d_in[2];   // (5120, 4096)
    float* out = (float*)d_out;                    // (100, 4096)

    k_prep      <<<256, 256, 0, stream>>>((const float4*)delays);
    k_input_part<<<JG * ICH, 128, 0, stream>>>(st, Wm, delays);
    k_input_red <<<256, 256, 0, stream>>>();
    k_sim       <<<NB, 256, 0, stream>>>(Wm, out);
}

// Round 29
// 1352.765 us; speedup vs baseline: 2.8699x; 1.0463x over previous
//
#include <hip/hip_runtime.h>
#include <math.h>

#pragma clang fp contract(off)

#define N      4096
#define INSZ   1024
#define KSP    8
#define NSTEP  100
#define NB     64      // sim blocks; block owns 64 columns
#define CPB    64      // columns per sim block
#define NCH    16      // deposit chunks (spike-list split)
#define ICH    8       // input i-chunks
#define JG     32      // input col-groups (128 cols each)
#define PUBW   16      // u64 words per publish slot (128B line per block-step)

// Static device scratch; g_pub cleared by k_prep each call (graph-replay safe).
__device__ float              g_I[NSTEP * N];                 // 1.6 MB
__device__ float              g_part[ICH * NSTEP * N];        // 13.1 MB
__device__ unsigned char      g_dbin[(size_t)N * N];          // 16 MB
// publish slots: [t][block] -> own 128B line; words 0,1 = (mask_half32<<32)|(t+1)
__device__ __align__(128) unsigned long long g_pub[NSTEP * NB * PUBW];  // 800 KB

// ---------- dbin = clip((int)(d*100.0f)+1, 1, 5), float4/uchar4 + pub reset ----------
__global__ __launch_bounds__(256) void k_prep(const float4* __restrict__ delays4) {
    int idx = blockIdx.x * 256 + threadIdx.x;
    int stride = gridDim.x * 256;
    for (int f = idx; f < NSTEP * NB * PUBW; f += stride) g_pub[f] = 0ull;
    const int tot4 = (N / 4) * N;                 // recurrent rows are first N rows
    for (int e = idx; e < tot4; e += stride) {
        float4 d4 = delays4[e];
        uchar4 o;
        { float d = fmaxf(d4.x, 0.0f); int db = (int)__fmul_rn(d, 100.0f) + 1; o.x = (unsigned char)(db > 5 ? 5 : db); }
        { float d = fmaxf(d4.y, 0.0f); int db = (int)__fmul_rn(d, 100.0f) + 1; o.y = (unsigned char)(db > 5 ? 5 : db); }
        { float d = fmaxf(d4.z, 0.0f); int db = (int)__fmul_rn(d, 100.0f) + 1; o.z = (unsigned char)(db > 5 ? 5 : db); }
        { float d = fmaxf(d4.w, 0.0f); int db = (int)__fmul_rn(d, 100.0f) + 1; o.w = (unsigned char)(db > 5 ? 5 : db); }
        *(uchar4*)&g_dbin[(size_t)e * 4] = o;
    }
}

// ---------- input binning partials: block = (jg, ic), 128 cols x 128 i-rows ----------
__global__ __launch_bounds__(128) void k_input_part(const float* __restrict__ st,
                                                    const float* __restrict__ Wm,
                                                    const float* __restrict__ delays) {
    __shared__ float acc[NSTEP * 128];            // 51.2 KB
    int jg = blockIdx.x & (JG - 1);
    int ic = blockIdx.x / JG;
    int tid = threadIdx.x;
    int j = jg * 128 + tid;
    for (int b = 0; b < NSTEP; b++) acc[b * 128 + tid] = 0.0f;
    __syncthreads();
    int i0 = ic * (INSZ / ICH);
    for (int ii = 0; ii < INSZ / ICH; ii++) {
        int i = i0 + ii;
        size_t base = (size_t)(N + i) * N + j;
        float d = fmaxf(delays[base], 0.0f);
        float w = Wm[base];
        const float* sp = st + i * KSP;
        #pragma unroll
        for (int k = 0; k < KSP; k++) {
            float tt = __fadd_rn(sp[k], d);       // f32 add (== np t_arr)
            float q  = __fmul_rn(tt, 100.0f);     // f32 multiply (== np *1/DT)
            if (q < 100.0f) {                     // bin <= 99 (q >= 0 always)
                int b = (int)q;
                atomicAdd(&acc[b * 128 + tid], w);   // ds_add_f32, per-lane ordered
            }
        }
    }
    __syncthreads();
    for (int b = 0; b < NSTEP; b++)
        g_part[((size_t)ic * NSTEP + b) * N + j] = acc[b * 128 + tid];
}

// ---------- ordered 8-way reduce of input partials ----------
__global__ __launch_bounds__(256) void k_input_red() {
    int idx = blockIdx.x * 256 + threadIdx.x;
    int stride = gridDim.x * 256;
    for (int e = idx; e < NSTEP * N; e += stride) {
        float s = 0.0f;
        #pragma unroll
        for (int c = 0; c < ICH; c++)             // ascending ic == ascending i
            s = __fadd_rn(s, g_part[(size_t)c * NSTEP * N + e]);
        g_I[e] = s;
    }
}

// ---------- simulation: 64 blocks x 256 threads, decontended publish lines ----------
__global__ __launch_bounds__(256, 1) void k_sim(const float* __restrict__ Wm,
                                                float* __restrict__ out) {
    int tid  = threadIdx.x;
    int blk  = blockIdx.x;
    int lane = tid & 63;

    __shared__ float          pbuf[NCH * 5 * CPB];   // [chunk][slot][col] 20 KB
    __shared__ float          I_lds[NSTEP * CPB];    // this block's I_in, 25.6 KB
    __shared__ float          Obuf[2][CPB];          // output ping-pong
    __shared__ unsigned short list[N];               // ascending spike list, 8 KB
    __shared__ int            s_cnt;

    for (int e = tid; e < NSTEP * CPB; e += 256) {   // preload I_in slice
        int t = e >> 6, c = e & 63;
        I_lds[e] = g_I[t * N + blk * CPB + c];
    }
    for (int e = tid; e < NCH * 5 * CPB; e += 256) pbuf[e] = 0.0f;
    __syncthreads();

    int quad  = tid & (NCH - 1);      // 0..15 -> 4 consecutive columns
    int chunk = tid >> 4;             // 0..15 -> spike-list chunk
    int col0  = blk * CPB + quad * 4;
    float v = 0.0f;                   // membrane state (wave 0 uses it)

    for (int t = 0; t < NSTEP; t++) {
        int slot = t % 5;
        unsigned long long expseq = (unsigned long long)(t + 1);

        if (tid < CPB) {
            // ---- wave 0: membrane update + fence-free publish (own 128B line) ----
            float bufv = 0.0f;
            #pragma unroll
            for (int c = 0; c < NCH; c++) {        // chunk-order reduce + clear
                int a = (c * 5 + slot) * CPB + tid;
                bufv = __fadd_rn(bufv, pbuf[a]);
                pbuf[a] = 0.0f;
            }
            float I  = __fadd_rn(I_lds[t * CPB + tid], bufv);
            float vn = __fadd_rn(__fadd_rn(v, __fmul_rn(0.1f, -v)), I);
            bool  spk = (vn >= 1.0f);
            float vo = spk ? 0.0f : vn;
            v = vo;
            unsigned long long m = __ballot(spk);
            if (tid == 0) {
                unsigned long long* slotp = &g_pub[(t * NB + blk) * PUBW];
                unsigned long long w0 = ((m & 0xFFFFFFFFull) << 32) | expseq;
                unsigned long long w1 = ((m >> 32) << 32) | expseq;
                __hip_atomic_store(&slotp[0], w0,
                                   __ATOMIC_RELAXED, __HIP_MEMORY_SCOPE_AGENT);
                __hip_atomic_store(&slotp[1], w1,
                                   __ATOMIC_RELAXED, __HIP_MEMORY_SCOPE_AGENT);
            }
            Obuf[t & 1][tid] = vo;                 // LDS only; store deferred
        } else if (tid < 128) {
            // ---- wave 1: backoff poll (lane L watches block L's line) + list ----
            const unsigned long long* slotp = &g_pub[(t * NB + lane) * PUBW];
            unsigned long long w0, w1;
            w0 = __hip_atomic_load(&slotp[0], __ATOMIC_RELAXED, __HIP_MEMORY_SCOPE_AGENT);
            w1 = __hip_atomic_load(&slotp[1], __ATOMIC_RELAXED, __HIP_MEMORY_SCOPE_AGENT);
            while ((unsigned)w0 != (unsigned)expseq ||
                   (unsigned)w1 != (unsigned)expseq) {
                __builtin_amdgcn_s_sleep(8);       // ~0.2 us backoff: cut LLC storm
                w0 = __hip_atomic_load(&slotp[0], __ATOMIC_RELAXED, __HIP_MEMORY_SCOPE_AGENT);
                w1 = __hip_atomic_load(&slotp[1], __ATOMIC_RELAXED, __HIP_MEMORY_SCOPE_AGENT);
            }
            unsigned long long mm = (w0 >> 32) | ((w1 >> 32) << 32);

            int pc = __popcll(mm);
            int incl = pc;
            #pragma unroll
            for (int o = 1; o < 64; o <<= 1) {
                int nbv = __shfl_up(incl, o, 64);
                if (lane >= o) incl += nbv;
            }
            int off = incl - pc;
            if (lane == 63) s_cnt = incl;
            while (mm) {
                int bb = __builtin_ctzll(mm);
                mm &= mm - 1;
                list[off++] = (unsigned short)((lane << 6) + bb);
            }
        } else if (tid < 192) {
            // ---- wave 2: store previous step's output (drain overlaps phase) ----
            if (t > 0)
                out[(t - 1) * N + blk * CPB + lane] = Obuf[(t - 1) & 1][lane];
        }
        __syncthreads();

        // ---- deposits: 16-way spike split, float4 cols, ds_add_f32 partials ----
        int S  = s_cnt;
        int lo = (S * chunk) >> 4;
        int hi = (S * (chunk + 1)) >> 4;
        float* pb = &pbuf[chunk * 5 * CPB];
        int cb = quad * 4;
        #pragma unroll 4
        for (int s = lo; s < hi; s++) {
            int i = (int)list[s];
            size_t base = (size_t)i * N + col0;
            float4 w4 = *(const float4*)&Wm[base];
            uchar4 d4 = *(const uchar4*)&g_dbin[base];
            int r0 = slot + d4.x; if (r0 >= 5) r0 -= 5;
            int r1 = slot + d4.y; if (r1 >= 5) r1 -= 5;
            int r2 = slot + d4.z; if (r2 >= 5) r2 -= 5;
            int r3 = slot + d4.w; if (r3 >= 5) r3 -= 5;
            atomicAdd(&pb[r0 * CPB + cb + 0], w4.x);
            atomicAdd(&pb[r1 * CPB + cb + 1], w4.y);
            atomicAdd(&pb[r2 * CPB + cb + 2], w4.z);
            atomicAdd(&pb[r3 * CPB + cb + 3], w4.w);
        }
        __syncthreads();
    }

    // final output row (t = NSTEP-1)
    if (tid < CPB)
        out[(NSTEP - 1) * N + blk * CPB + tid] = Obuf[(NSTEP - 1) & 1][tid];
}

extern "C" void kernel_launch(void* const* d_in, const int* in_sizes, int n_in,
                              void* d_out, int out_size, void* d_ws, size_t ws_size,
                              hipStream_t stream) {
    const float* st     = (const float*)d_in[0];   // (1024, 8)
    const float* Wm     = (const float*)d_in[1];   // (5120, 4096)
    const float* delays = (const float*)d_in[2];   // (5120, 4096)
    float* out = (float*)d_out;                    // (100, 4096)

    k_prep      <<<256, 256, 0, stream>>>((const float4*)delays);
    k_input_part<<<JG * ICH, 128, 0, stream>>>(st, Wm, delays);
    k_input_red <<<256, 256, 0, stream>>>();
    k_sim       <<<NB, 256, 0, stream>>>(Wm, out);
}